// Round 3
// baseline (925.098 us; speedup 1.0000x reference)
//
#include <hip/hip_runtime.h>
#include <math.h>

#define NA 10000
#define NE 250000
#define FD 128
#define NRBF 20
#define RCUT 5.0f

typedef _Float16 h16;
typedef __attribute__((ext_vector_type(8))) _Float16 half8;
typedef __attribute__((ext_vector_type(2))) _Float16 half2v;
typedef __attribute__((ext_vector_type(4))) float f32x4;

static __device__ __forceinline__ half8 f32x8_to_h8(const float* p) {
    float4 a = *(const float4*)p;
    float4 b = *(const float4*)(p + 4);
    half8 r;
    r[0] = (h16)a.x; r[1] = (h16)a.y; r[2] = (h16)a.z; r[3] = (h16)a.w;
    r[4] = (h16)b.x; r[5] = (h16)b.y; r[6] = (h16)b.z; r[7] = (h16)b.w;
    return r;
}

// ---------------- single-wave GEMM: 16 rows, N=NT*16 cols, A f16 [M,K] ------
template<int NT>
__global__ __launch_bounds__(64) void wgemm_kernel(
    const h16* __restrict__ A, const h16* __restrict__ Bt,
    const float* __restrict__ bias, float* __restrict__ Cf, h16* __restrict__ Ch,
    int K, int act)
{
    const int lane = threadIdx.x;
    const int ar = lane & 15, kg = lane >> 4;
    const size_t row0 = (size_t)blockIdx.x * 16;
    f32x4 acc[NT] = {};
    for (int ks = 0; ks < K; ks += 32) {
        int k = ks + kg * 8;
        half8 af = *(const half8*)&A[(row0 + ar) * K + k];
#pragma unroll
        for (int t = 0; t < NT; ++t) {
            half8 bf = *(const half8*)&Bt[(size_t)(t * 16 + ar) * K + k];
            acc[t] = __builtin_amdgcn_mfma_f32_16x16x32_f16(af, bf, acc[t], 0, 0, 0);
        }
    }
    const int N = NT * 16;
#pragma unroll
    for (int t = 0; t < NT; ++t) {
        int col = t * 16 + ar;
        float bb = bias ? bias[col] : 0.f;
#pragma unroll
        for (int r = 0; r < 4; ++r) {
            size_t row = row0 + kg * 4 + r;
            float v = acc[t][r] + bb;
            if (act) v = v / (1.f + expf(-v));
            if (Cf) Cf[row * N + col] = v;
            if (Ch) Ch[row * N + col] = (h16)v;
        }
    }
}

// ---------------- fused interaction MLP: x16 = silu(q@W1+b1)@W2+b2 ---------
__global__ __launch_bounds__(64) void intmlp_kernel(
    const float* __restrict__ q, const h16* __restrict__ W1t, const float* __restrict__ b1,
    const h16* __restrict__ W2t, const float* __restrict__ b2, h16* __restrict__ x16)
{
    __shared__ h16 Hs[16 * 136];
    const int lane = threadIdx.x;
    const int ar = lane & 15, kg = lane >> 4;
    const size_t row0 = (size_t)blockIdx.x * 16;
    f32x4 a1[8] = {};
    for (int ks = 0; ks < 128; ks += 32) {
        int k = ks + kg * 8;
        half8 af = f32x8_to_h8(q + (row0 + ar) * 128 + k);
#pragma unroll
        for (int t = 0; t < 8; ++t) {
            half8 bf = *(const half8*)&W1t[(size_t)(t * 16 + ar) * 128 + k];
            a1[t] = __builtin_amdgcn_mfma_f32_16x16x32_f16(af, bf, a1[t], 0, 0, 0);
        }
    }
#pragma unroll
    for (int t = 0; t < 8; ++t) {
        float bb = b1[t * 16 + ar];
#pragma unroll
        for (int r = 0; r < 4; ++r) {
            float v = a1[t][r] + bb;
            v = v / (1.f + expf(-v));
            Hs[(kg * 4 + r) * 136 + t * 16 + ar] = (h16)v;
        }
    }
    __syncthreads();
    f32x4 a2[24] = {};
    for (int ks = 0; ks < 128; ks += 32) {
        int k = ks + kg * 8;
        half8 af = *(const half8*)&Hs[ar * 136 + k];
#pragma unroll
        for (int t = 0; t < 24; ++t) {
            half8 bf = *(const half8*)&W2t[(size_t)(t * 16 + ar) * 128 + k];
            a2[t] = __builtin_amdgcn_mfma_f32_16x16x32_f16(af, bf, a2[t], 0, 0, 0);
        }
    }
#pragma unroll
    for (int t = 0; t < 24; ++t) {
        int col = t * 16 + ar;
        float bb = b2[col];
#pragma unroll
        for (int r = 0; r < 4; ++r)
            x16[(row0 + kg * 4 + r) * 384 + col] = (h16)(a2[t][r] + bb);
    }
}

// ------- fused mixing MLP: ctx built inline, update fused into epilogue -----
__global__ __launch_bounds__(64) void mixmlp_kernel(
    const h16* __restrict__ mumix, const h16* __restrict__ W1t, const float* __restrict__ b1,
    const h16* __restrict__ W2t, const float* __restrict__ b2,
    float* __restrict__ q, float* __restrict__ mu, h16* __restrict__ mu16)
{
    __shared__ h16 Hs[16 * 136];
    const int lane = threadIdx.x;
    const int ar = lane & 15, kg = lane >> 4;
    const size_t row0 = (size_t)blockIdx.x * 16;
    const size_t na = row0 + ar;
    f32x4 a1[8] = {};
    for (int ks = 0; ks < 256; ks += 32) {
        int k = ks + kg * 8;
        half8 af;
        if (ks < 128) {
            af = f32x8_to_h8(q + na * 128 + k);
        } else {
            int fo = k - 128;
            half8 v0 = *(const half8*)&mumix[(na * 3 + 0) * 256 + fo];
            half8 v1 = *(const half8*)&mumix[(na * 3 + 1) * 256 + fo];
            half8 v2 = *(const half8*)&mumix[(na * 3 + 2) * 256 + fo];
#pragma unroll
            for (int jj = 0; jj < 8; ++jj) {
                float a = (float)v0[jj], b = (float)v1[jj], c = (float)v2[jj];
                af[jj] = (h16)sqrtf(a * a + b * b + c * c + 1e-8f);
            }
        }
#pragma unroll
        for (int t = 0; t < 8; ++t) {
            half8 bf = *(const half8*)&W1t[(size_t)(t * 16 + ar) * 256 + k];
            a1[t] = __builtin_amdgcn_mfma_f32_16x16x32_f16(af, bf, a1[t], 0, 0, 0);
        }
    }
#pragma unroll
    for (int t = 0; t < 8; ++t) {
        float bb = b1[t * 16 + ar];
#pragma unroll
        for (int r = 0; r < 4; ++r) {
            float v = a1[t][r] + bb;
            v = v / (1.f + expf(-v));
            Hs[(kg * 4 + r) * 136 + t * 16 + ar] = (h16)v;
        }
    }
    __syncthreads();
    f32x4 a2[24] = {};
    for (int ks = 0; ks < 128; ks += 32) {
        int k = ks + kg * 8;
        half8 af = *(const half8*)&Hs[ar * 136 + k];
#pragma unroll
        for (int t = 0; t < 24; ++t) {
            half8 bf = *(const half8*)&W2t[(size_t)(t * 16 + ar) * 128 + k];
            a2[t] = __builtin_amdgcn_mfma_f32_16x16x32_f16(af, bf, a2[t], 0, 0, 0);
        }
    }
    // fused update: dq/dm/dqm for feature f live in tiles t, t+8, t+16, same lane
#pragma unroll
    for (int t = 0; t < 8; ++t) {
        int fo = t * 16 + ar;
        float bdq = b2[fo], bdm = b2[128 + fo], bdqm = b2[256 + fo];
#pragma unroll
        for (int r = 0; r < 4; ++r) {
            size_t n = row0 + kg * 4 + r;
            float dq = a2[t][r] + bdq;
            float dm = a2[t + 8][r] + bdm;
            float dqm = a2[t + 16][r] + bdqm;
            const h16* mm = mumix + n * 3 * 256;
            float v0 = (float)mm[fo],       w0 = (float)mm[128 + fo];
            float v1 = (float)mm[256 + fo], w1 = (float)mm[384 + fo];
            float v2 = (float)mm[512 + fo], w2 = (float)mm[640 + fo];
            float sv = v0 * w0 + v1 * w1 + v2 * w2;
            q[n * 128 + fo] += dq + dqm * sv;
            size_t b = n * 384 + fo;
            float m0 = mu[b] + dm * w0;
            float m1 = mu[b + 128] + dm * w1;
            float m2 = mu[b + 256] + dm * w2;
            mu[b] = m0; mu[b + 128] = m1; mu[b + 256] = m2;
            mu16[b] = (h16)m0; mu16[b + 128] = (h16)m1; mu16[b + 256] = (h16)m2;
        }
    }
}

// ---------------- geometry: dir + padded phi_hat = [phi*fcut, fcut, 0...] ---
__global__ void geom_kernel(const float* __restrict__ R,
                            const int* __restrict__ idx_i,
                            const int* __restrict__ idx_j,
                            const float* __restrict__ offsets,
                            float* __restrict__ dir, h16* __restrict__ ph)
{
    int e = blockIdx.x * blockDim.x + threadIdx.x;
    if (e >= NE) return;
    int i = idx_i[e], j = idx_j[e];
    float rx = R[j * 3 + 0] - R[i * 3 + 0] + offsets[e * 3 + 0];
    float ry = R[j * 3 + 1] - R[i * 3 + 1] + offsets[e * 3 + 1];
    float rz = R[j * 3 + 2] - R[i * 3 + 2] + offsets[e * 3 + 2];
    float d = sqrtf(rx * rx + ry * ry + rz * rz);
    float inv = 1.f / d;
    float fcut = 0.f;
    if (d < RCUT) fcut = 0.5f * (cosf(d * (3.14159265358979323846f / RCUT)) + 1.f);
    float4 g = make_float4(rx * inv, ry * inv, rz * inv, 0.f);
    *(float4*)&dir[(size_t)e * 4] = g;
    h16* pp = ph + (size_t)e * 32;
    const float delta = RCUT / 19.f;
    const float coeff = -0.5f / (delta * delta);
#pragma unroll
    for (int r = 0; r < NRBF; ++r) {
        float dc = d - (float)r * delta;
        pp[r] = (h16)(expf(coeff * dc * dc) * fcut);
    }
    pp[20] = (h16)fcut;
#pragma unroll
    for (int r = 21; r < 32; ++r) pp[r] = (h16)0.f;
}

// ---------------- CSR row offsets (idx_i sorted) ----------------
__global__ void csr_kernel(const int* __restrict__ idx_i, int* __restrict__ row_start)
{
    int n = blockIdx.x * blockDim.x + threadIdx.x;
    if (n > NA) return;
    int lo = 0, hi = NE;
    while (lo < hi) {
        int mid = (lo + hi) >> 1;
        if (idx_i[mid] < n) lo = mid + 1; else hi = mid;
    }
    row_start[n] = lo;
}

// ---------------- init ----------------
__global__ __launch_bounds__(128) void init_kernel(const int* __restrict__ Z,
                                                   const float* __restrict__ emb,
                                                   float* __restrict__ q,
                                                   float* __restrict__ mu_ws,
                                                   h16* __restrict__ mu16a)
{
    int n = blockIdx.x, f = threadIdx.x;
    q[(size_t)n * FD + f] = emb[(size_t)Z[n] * FD + f];
    float* m = mu_ws + (size_t)n * 384;
    m[f] = 0.f; m[128 + f] = 0.f; m[256 + f] = 0.f;
    h16* m16 = mu16a + (size_t)n * 384;
    m16[f] = (h16)0.f; m16[128 + f] = (h16)0.f; m16[256 + f] = (h16)0.f;
}

// ---------------- weight transpose fp32[K][N] -> f16[N][K] ----------------
__global__ void wtrans_kernel(const float* __restrict__ W, h16* __restrict__ Bt,
                              int K, int N)
{
    int idx = blockIdx.x * 256 + threadIdx.x;
    int total = K * N;
    if (idx >= total) return;
    int n = idx / K, k = idx - n * K;
    Bt[(size_t)blockIdx.y * total + idx] =
        (h16)W[(size_t)blockIdx.y * total + (size_t)k * N + n];
}

// ---------------- filter weights: fwt[n][k] = filt_W[k][n] | filt_b | 0 -----
__global__ void filtprep_kernel(const float* __restrict__ filt_W,
                                const float* __restrict__ filt_b,
                                h16* __restrict__ fwt)
{
    int idx = blockIdx.x * 256 + threadIdx.x;
    if (idx >= 384 * 32) return;
    int n = idx >> 5, k = idx & 31;
    float v = 0.f;
    if (k < 20) v = filt_W[k * 384 + n];
    else if (k == 20) v = filt_b[n];
    fwt[idx] = (h16)v;
}

// ---------------- edge message passing ----------------
__global__ __launch_bounds__(128) void edge_kernel(
    const float* __restrict__ dir, const h16* __restrict__ ph,
    const h16* __restrict__ fwt, const h16* __restrict__ W16,
    const int* __restrict__ row_start, const int* __restrict__ idx_j,
    const h16* __restrict__ x16, const h16* __restrict__ mu16p,
    const float* __restrict__ mup, float* __restrict__ mun,
    h16* __restrict__ mu16n, float* __restrict__ q)
{
    const int n = blockIdx.x, f = threadIdx.x;
    half2v fa[11], fb[11], fc[11];
    if (!W16) {
        const half2v* pa = (const half2v*)(fwt + (size_t)f * 32);
        const half2v* pb = (const half2v*)(fwt + (size_t)(128 + f) * 32);
        const half2v* pc = (const half2v*)(fwt + (size_t)(256 + f) * 32);
#pragma unroll
        for (int r = 0; r < 11; ++r) { fa[r] = pa[r]; fb[r] = pb[r]; fc[r] = pc[r]; }
    }
    float accq = 0.f, am0 = 0.f, am1 = 0.f, am2 = 0.f;
    const int e0 = row_start[n], e1 = row_start[n + 1];
    for (int e = e0; e < e1; ++e) {
        float w0, w1, w2;
        if (W16) {
            const h16* wp = W16 + (size_t)e * 384;
            w0 = (float)wp[f]; w1 = (float)wp[128 + f]; w2 = (float)wp[256 + f];
        } else {
            half2v pr[12];
            const h16* pb8 = ph + (size_t)e * 32;
            *(half8*)&pr[0] = *(const half8*)pb8;
            *(half8*)&pr[4] = *(const half8*)(pb8 + 8);
            *(half8*)&pr[8] = *(const half8*)(pb8 + 16);
            half2v A0 = {(h16)0.f, (h16)0.f}, A1 = A0, A2 = A0;
#pragma unroll
            for (int r = 0; r < 11; ++r) {
                A0 = pr[r] * fa[r] + A0;
                A1 = pr[r] * fb[r] + A1;
                A2 = pr[r] * fc[r] + A2;
            }
            w0 = (float)A0[0] + (float)A0[1];
            w1 = (float)A1[0] + (float)A1[1];
            w2 = (float)A2[0] + (float)A2[1];
        }
        int j = idx_j[e];
        float4 g = *(const float4*)&dir[(size_t)e * 4];
        const h16* xb = x16 + (size_t)j * 384;
        const h16* mb = mu16p + (size_t)j * 384;
        float x0 = (float)xb[f], x1 = (float)xb[128 + f], x2 = (float)xb[256 + f];
        accq = fmaf(w0, x0, accq);
        float xw1 = w1 * x1, xw2 = w2 * x2;
        am0 += xw1 * g.x + xw2 * (float)mb[f];
        am1 += xw1 * g.y + xw2 * (float)mb[128 + f];
        am2 += xw1 * g.z + xw2 * (float)mb[256 + f];
    }
    q[(size_t)n * FD + f] += accq;
    size_t b = (size_t)n * 384;
    float m0 = mup[b + f] + am0;
    float m1 = mup[b + 128 + f] + am1;
    float m2 = mup[b + 256 + f] + am2;
    mun[b + f] = m0; mun[b + 128 + f] = m1; mun[b + 256 + f] = m2;
    mu16n[b + f] = (h16)m0; mu16n[b + 128 + f] = (h16)m1; mu16n[b + 256 + f] = (h16)m2;
}

// ---------------- launch ----------------
extern "C" void kernel_launch(void* const* d_in, const int* in_sizes, int n_in,
                              void* d_out, int out_size, void* d_ws, size_t ws_size,
                              hipStream_t stream)
{
    const int*   Z       = (const int*)d_in[0];
    const float* R       = (const float*)d_in[1];
    const int*   idx_i   = (const int*)d_in[2];
    const int*   idx_j   = (const int*)d_in[3];
    const float* offsets = (const float*)d_in[4];
    const float* emb     = (const float*)d_in[5];
    const float* filt_W  = (const float*)d_in[6];
    const float* filt_b  = (const float*)d_in[7];
    const float* int_W1  = (const float*)d_in[8];
    const float* int_b1  = (const float*)d_in[9];
    const float* int_W2  = (const float*)d_in[10];
    const float* int_b2  = (const float*)d_in[11];
    const float* mix_Wmu = (const float*)d_in[12];
    const float* mix_W1  = (const float*)d_in[13];
    const float* mix_b1  = (const float*)d_in[14];
    const float* mix_W2  = (const float*)d_in[15];
    const float* mix_b2  = (const float*)d_in[16];

    float* q_out  = (float*)d_out;
    float* mu_out = (float*)d_out + (size_t)NA * FD;

    char* base = (char*)d_ws;
    size_t o = 0;
    auto alloc = [&](size_t bytes) -> void* {
        void* p = base + o;
        o += (bytes + 255) & ~(size_t)255;
        return p;
    };
    float* dir    = (float*)alloc((size_t)NE * 4 * 4);
    h16*   ph     = (h16*)alloc((size_t)NE * 32 * 2);
    h16*   x16    = (h16*)alloc((size_t)NA * 384 * 2);
    h16*   mu16a  = (h16*)alloc((size_t)NA * 384 * 2);
    h16*   mu16b  = (h16*)alloc((size_t)NA * 384 * 2);
    float* mu_ws  = (float*)alloc((size_t)NA * 384 * 4);
    h16*   mumix  = (h16*)alloc((size_t)NA * 3 * 256 * 2);
    h16*   W1t    = (h16*)alloc((size_t)3 * 128 * 128 * 2);
    h16*   W2t    = (h16*)alloc((size_t)3 * 384 * 128 * 2);
    h16*   WmuT   = (h16*)alloc((size_t)3 * 256 * 128 * 2);
    h16*   mW1t   = (h16*)alloc((size_t)3 * 128 * 256 * 2);
    h16*   mW2t   = (h16*)alloc((size_t)3 * 384 * 128 * 2);
    h16*   fwt    = (h16*)alloc((size_t)384 * 32 * 2);
    int*   row_st = (int*)alloc((size_t)(NA + 1) * 4);
    h16*   W16    = nullptr;
    if (o + (size_t)NE * 384 * 2 <= ws_size)
        W16 = (h16*)alloc((size_t)NE * 384 * 2);

    // setup
    geom_kernel<<<(NE + 255) / 256, 256, 0, stream>>>(R, idx_i, idx_j, offsets, dir, ph);
    csr_kernel<<<(NA + 256) / 256, 256, 0, stream>>>(idx_i, row_st);
    init_kernel<<<NA, 128, 0, stream>>>(Z, emb, q_out, mu_ws, mu16a);
    wtrans_kernel<<<dim3((128 * 128 + 255) / 256, 3), 256, 0, stream>>>(int_W1, W1t, 128, 128);
    wtrans_kernel<<<dim3((128 * 384 + 255) / 256, 3), 256, 0, stream>>>(int_W2, W2t, 128, 384);
    wtrans_kernel<<<dim3((128 * 256 + 255) / 256, 3), 256, 0, stream>>>(mix_Wmu, WmuT, 128, 256);
    wtrans_kernel<<<dim3((256 * 128 + 255) / 256, 3), 256, 0, stream>>>(mix_W1, mW1t, 256, 128);
    wtrans_kernel<<<dim3((128 * 384 + 255) / 256, 3), 256, 0, stream>>>(mix_W2, mW2t, 128, 384);
    filtprep_kernel<<<(384 * 32 + 255) / 256, 256, 0, stream>>>(filt_W, filt_b, fwt);
    if (W16)
        wgemm_kernel<24><<<NE / 16, 64, 0, stream>>>(ph, fwt, nullptr, nullptr, W16, 32, 0);

    for (int it = 0; it < 3; ++it) {
        const h16*   W1i  = W1t  + (size_t)it * 128 * 128;
        const float* b1i  = int_b1 + (size_t)it * 128;
        const h16*   W2i  = W2t  + (size_t)it * 384 * 128;
        const float* b2i  = int_b2 + (size_t)it * 384;
        const h16*   Wmui = WmuT + (size_t)it * 256 * 128;
        const h16*   mW1i = mW1t + (size_t)it * 128 * 256;
        const float* mb1i = mix_b1 + (size_t)it * 128;
        const h16*   mW2i = mW2t + (size_t)it * 384 * 128;
        const float* mb2i = mix_b2 + (size_t)it * 384;

        float* mu_prev = (it & 1) ? mu_out : mu_ws;
        float* mu_next = (it & 1) ? mu_ws : mu_out;
        h16*   m16p    = (it & 1) ? mu16b : mu16a;
        h16*   m16n    = (it & 1) ? mu16a : mu16b;

        intmlp_kernel<<<NA / 16, 64, 0, stream>>>(q_out, W1i, b1i, W2i, b2i, x16);
        edge_kernel<<<NA, 128, 0, stream>>>(dir, ph, fwt, W16, row_st, idx_j,
                                            x16, m16p, mu_prev, mu_next, m16n, q_out);
        wgemm_kernel<16><<<3 * NA / 16, 64, 0, stream>>>(m16n, Wmui, nullptr, nullptr,
                                                         mumix, 128, 0);
        mixmlp_kernel<<<NA / 16, 64, 0, stream>>>(mumix, mW1i, mb1i, mW2i, mb2i,
                                                  q_out, mu_next, m16n);
    }
}

// Round 4
// 489.573 us; speedup vs baseline: 1.8896x; 1.8896x over previous
//
#include <hip/hip_runtime.h>
#include <math.h>

#define NA 10000
#define NE 250000
#define FD 128
#define NRBF 20
#define RCUT 5.0f

typedef _Float16 h16;
typedef __attribute__((ext_vector_type(8))) _Float16 half8;
typedef __attribute__((ext_vector_type(2))) _Float16 half2v;
typedef __attribute__((ext_vector_type(4))) float f32x4;

static __device__ __forceinline__ half8 f32x8_to_h8(const float* p) {
    float4 a = *(const float4*)p;
    float4 b = *(const float4*)(p + 4);
    half8 r;
    r[0] = (h16)a.x; r[1] = (h16)a.y; r[2] = (h16)a.z; r[3] = (h16)a.w;
    r[4] = (h16)b.x; r[5] = (h16)b.y; r[6] = (h16)b.z; r[7] = (h16)b.w;
    return r;
}
static __device__ __forceinline__ float silu(float v) {
    return v / (1.f + expf(-v));
}

// ====== fused interaction MLP: x16 = silu(q@W1+b1)@W2+b2 ======
// block = 16 atoms, 4 waves; waves split the N dimension.
__global__ __launch_bounds__(256) void intmlp_kernel(
    const float* __restrict__ q, const h16* __restrict__ W1t, const float* __restrict__ b1,
    const h16* __restrict__ W2t, const float* __restrict__ b2, h16* __restrict__ x16)
{
    __shared__ h16 Hs[16 * 136];
    const int tid = threadIdx.x;
    const int wave = tid >> 6, lane = tid & 63;
    const int ar = lane & 15, kg = lane >> 4;
    const size_t row0 = (size_t)blockIdx.x * 16;

    // layer 1: wave handles col tiles 2w, 2w+1
    f32x4 a1[2] = {};
    for (int ks = 0; ks < 128; ks += 32) {
        int k = ks + kg * 8;
        half8 af = f32x8_to_h8(q + (row0 + ar) * 128 + k);
#pragma unroll
        for (int tt = 0; tt < 2; ++tt) {
            int t = wave * 2 + tt;
            half8 bf = *(const half8*)&W1t[(size_t)(t * 16 + ar) * 128 + k];
            a1[tt] = __builtin_amdgcn_mfma_f32_16x16x32_f16(af, bf, a1[tt], 0, 0, 0);
        }
    }
#pragma unroll
    for (int tt = 0; tt < 2; ++tt) {
        int col = (wave * 2 + tt) * 16 + ar;
        float bb = b1[col];
#pragma unroll
        for (int r = 0; r < 4; ++r)
            Hs[(kg * 4 + r) * 136 + col] = (h16)silu(a1[tt][r] + bb);
    }
    __syncthreads();
    // layer 2: wave handles col tiles 6w .. 6w+5
    f32x4 a2[6] = {};
    for (int ks = 0; ks < 128; ks += 32) {
        int k = ks + kg * 8;
        half8 af = *(const half8*)&Hs[ar * 136 + k];
#pragma unroll
        for (int tt = 0; tt < 6; ++tt) {
            int t = wave * 6 + tt;
            half8 bf = *(const half8*)&W2t[(size_t)(t * 16 + ar) * 128 + k];
            a2[tt] = __builtin_amdgcn_mfma_f32_16x16x32_f16(af, bf, a2[tt], 0, 0, 0);
        }
    }
#pragma unroll
    for (int tt = 0; tt < 6; ++tt) {
        int col = (wave * 6 + tt) * 16 + ar;
        float bb = b2[col];
#pragma unroll
        for (int r = 0; r < 4; ++r)
            x16[(row0 + kg * 4 + r) * 384 + col] = (h16)(a2[tt][r] + bb);
    }
}

// ====== fused mixing: mumix GEMM (LDS) + ctx + MLP + update ======
// block = 16 atoms, 4 waves.
__global__ __launch_bounds__(256) void mixfused_kernel(
    const h16* __restrict__ mu16n, const h16* __restrict__ WmuT,
    const h16* __restrict__ W1t, const float* __restrict__ b1,
    const h16* __restrict__ W2t, const float* __restrict__ b2,
    float* __restrict__ q, float* __restrict__ mu, h16* __restrict__ mu16w)
{
    __shared__ h16 MM[48 * 264];   // mumix [48 rows][256]
    __shared__ h16 CT[16 * 264];   // ctx   [16][256]
    __shared__ h16 Hs[16 * 136];   // hidden
    __shared__ h16 XM[16 * 392];   // xm    [16][384]
    const int tid = threadIdx.x;
    const int wave = tid >> 6, lane = tid & 63;
    const int ar = lane & 15, kg = lane >> 4;
    const size_t row0 = (size_t)blockIdx.x * 16;

    // ---- phase 1: mumix = mu @ Wmu, rows 48 (=16 atoms x 3 dirs), cols 256
    {
        f32x4 acc[3][4] = {};
        int aloc[3], dloc[3];
#pragma unroll
        for (int rt = 0; rt < 3; ++rt) {
            int rr = rt * 16 + ar;
            aloc[rt] = rr / 3;
            dloc[rt] = rr - 3 * aloc[rt];
        }
        for (int ks = 0; ks < 128; ks += 32) {
            int k = ks + kg * 8;
            half8 afr[3];
#pragma unroll
            for (int rt = 0; rt < 3; ++rt)
                afr[rt] = *(const half8*)&mu16n[(row0 + aloc[rt]) * 384 + dloc[rt] * 128 + k];
#pragma unroll
            for (int ct = 0; ct < 4; ++ct) {
                int c = wave * 4 + ct;
                half8 bf = *(const half8*)&WmuT[(size_t)(c * 16 + ar) * 128 + k];
#pragma unroll
                for (int rt = 0; rt < 3; ++rt)
                    acc[rt][ct] = __builtin_amdgcn_mfma_f32_16x16x32_f16(afr[rt], bf, acc[rt][ct], 0, 0, 0);
            }
        }
#pragma unroll
        for (int rt = 0; rt < 3; ++rt)
#pragma unroll
            for (int ct = 0; ct < 4; ++ct) {
                int col = (wave * 4 + ct) * 16 + ar;
#pragma unroll
                for (int r = 0; r < 4; ++r)
                    MM[(rt * 16 + kg * 4 + r) * 264 + col] = (h16)acc[rt][ct][r];
            }
    }
    __syncthreads();

    // ---- phase 2: ctx = [q, ||mu_V||]
    {
        int a = tid >> 4, fi = (tid & 15) * 8;
        const float* qp = q + (row0 + a) * 128 + fi;
        float4 q0 = *(const float4*)qp;
        float4 q1 = *(const float4*)(qp + 4);
        float qv[8] = {q0.x, q0.y, q0.z, q0.w, q1.x, q1.y, q1.z, q1.w};
#pragma unroll
        for (int jj = 0; jj < 8; ++jj) {
            int f = fi + jj;
            float v0 = (float)MM[(a * 3 + 0) * 264 + f];
            float v1 = (float)MM[(a * 3 + 1) * 264 + f];
            float v2 = (float)MM[(a * 3 + 2) * 264 + f];
            CT[a * 264 + 128 + f] = (h16)sqrtf(v0 * v0 + v1 * v1 + v2 * v2 + 1e-8f);
            CT[a * 264 + f] = (h16)qv[jj];
        }
    }
    __syncthreads();

    // ---- phase 3: h = silu(ctx @ mW1 + b1), 16x128, K=256
    {
        f32x4 a1[2] = {};
        for (int ks = 0; ks < 256; ks += 32) {
            int k = ks + kg * 8;
            half8 af = *(const half8*)&CT[ar * 264 + k];
#pragma unroll
            for (int tt = 0; tt < 2; ++tt) {
                int t = wave * 2 + tt;
                half8 bf = *(const half8*)&W1t[(size_t)(t * 16 + ar) * 256 + k];
                a1[tt] = __builtin_amdgcn_mfma_f32_16x16x32_f16(af, bf, a1[tt], 0, 0, 0);
            }
        }
#pragma unroll
        for (int tt = 0; tt < 2; ++tt) {
            int col = (wave * 2 + tt) * 16 + ar;
            float bb = b1[col];
#pragma unroll
            for (int r = 0; r < 4; ++r)
                Hs[(kg * 4 + r) * 136 + col] = (h16)silu(a1[tt][r] + bb);
        }
    }
    __syncthreads();

    // ---- phase 4: xm = h @ mW2 + b2, 16x384
    {
        f32x4 a2[6] = {};
        for (int ks = 0; ks < 128; ks += 32) {
            int k = ks + kg * 8;
            half8 af = *(const half8*)&Hs[ar * 136 + k];
#pragma unroll
            for (int tt = 0; tt < 6; ++tt) {
                int t = wave * 6 + tt;
                half8 bf = *(const half8*)&W2t[(size_t)(t * 16 + ar) * 128 + k];
                a2[tt] = __builtin_amdgcn_mfma_f32_16x16x32_f16(af, bf, a2[tt], 0, 0, 0);
            }
        }
#pragma unroll
        for (int tt = 0; tt < 6; ++tt) {
            int col = (wave * 6 + tt) * 16 + ar;
            float bb = b2[col];
#pragma unroll
            for (int r = 0; r < 4; ++r)
                XM[(kg * 4 + r) * 392 + col] = (h16)(a2[tt][r] + bb);
        }
    }
    __syncthreads();

    // ---- phase 5: fused update
    {
        int a = tid >> 4, fi = (tid & 15) * 8;
        size_t n = row0 + a;
#pragma unroll
        for (int jj = 0; jj < 8; ++jj) {
            int f = fi + jj;
            float dq  = (float)XM[a * 392 + f];
            float dm  = (float)XM[a * 392 + 128 + f];
            float dqm = (float)XM[a * 392 + 256 + f];
            float v0 = (float)MM[(a * 3 + 0) * 264 + f], w0 = (float)MM[(a * 3 + 0) * 264 + 128 + f];
            float v1 = (float)MM[(a * 3 + 1) * 264 + f], w1 = (float)MM[(a * 3 + 1) * 264 + 128 + f];
            float v2 = (float)MM[(a * 3 + 2) * 264 + f], w2 = (float)MM[(a * 3 + 2) * 264 + 128 + f];
            float sv = v0 * w0 + v1 * w1 + v2 * w2;
            q[n * 128 + f] += dq + dqm * sv;
            size_t b = n * 384 + f;
            float m0 = mu[b] + dm * w0;
            float m1 = mu[b + 128] + dm * w1;
            float m2 = mu[b + 256] + dm * w2;
            mu[b] = m0; mu[b + 128] = m1; mu[b + 256] = m2;
            mu16w[b] = (h16)m0; mu16w[b + 128] = (h16)m1; mu16w[b + 256] = (h16)m2;
        }
    }
}

// ====== geometry: dir + padded phi_hat = [phi*fcut (20), fcut, 0...] ======
__global__ void geom_kernel(const float* __restrict__ R,
                            const int* __restrict__ idx_i,
                            const int* __restrict__ idx_j,
                            const float* __restrict__ offsets,
                            float* __restrict__ dir, h16* __restrict__ ph)
{
    int e = blockIdx.x * blockDim.x + threadIdx.x;
    if (e >= NE) return;
    int i = idx_i[e], j = idx_j[e];
    float rx = R[j * 3 + 0] - R[i * 3 + 0] + offsets[e * 3 + 0];
    float ry = R[j * 3 + 1] - R[i * 3 + 1] + offsets[e * 3 + 1];
    float rz = R[j * 3 + 2] - R[i * 3 + 2] + offsets[e * 3 + 2];
    float d = sqrtf(rx * rx + ry * ry + rz * rz);
    float inv = 1.f / d;
    float fcut = 0.f;
    if (d < RCUT) fcut = 0.5f * (cosf(d * (3.14159265358979323846f / RCUT)) + 1.f);
    *(float4*)&dir[(size_t)e * 4] = make_float4(rx * inv, ry * inv, rz * inv, 0.f);
    h16* pp = ph + (size_t)e * 32;
    const float delta = RCUT / 19.f;
    const float coeff = -0.5f / (delta * delta);
#pragma unroll
    for (int r = 0; r < NRBF; ++r) {
        float dc = d - (float)r * delta;
        pp[r] = (h16)(expf(coeff * dc * dc) * fcut);
    }
    pp[20] = (h16)fcut;
#pragma unroll
    for (int r = 21; r < 32; ++r) pp[r] = (h16)0.f;
}

// ====== CSR row offsets (idx_i sorted) ======
__global__ void csr_kernel(const int* __restrict__ idx_i, int* __restrict__ row_start)
{
    int n = blockIdx.x * blockDim.x + threadIdx.x;
    if (n > NA) return;
    int lo = 0, hi = NE;
    while (lo < hi) {
        int mid = (lo + hi) >> 1;
        if (idx_i[mid] < n) lo = mid + 1; else hi = mid;
    }
    row_start[n] = lo;
}

// ====== init ======
__global__ __launch_bounds__(128) void init_kernel(const int* __restrict__ Z,
                                                   const float* __restrict__ emb,
                                                   float* __restrict__ q,
                                                   float* __restrict__ mu_ws,
                                                   h16* __restrict__ mu16a)
{
    int n = blockIdx.x, f = threadIdx.x;
    q[(size_t)n * FD + f] = emb[(size_t)Z[n] * FD + f];
    float* m = mu_ws + (size_t)n * 384;
    m[f] = 0.f; m[128 + f] = 0.f; m[256 + f] = 0.f;
    h16* m16 = mu16a + (size_t)n * 384;
    m16[f] = (h16)0.f; m16[128 + f] = (h16)0.f; m16[256 + f] = (h16)0.f;
}

// ====== weight transpose fp32[K][N] -> f16[N][K] ======
__global__ void wtrans_kernel(const float* __restrict__ W, h16* __restrict__ Bt,
                              int K, int N)
{
    int idx = blockIdx.x * 256 + threadIdx.x;
    int total = K * N;
    if (idx >= total) return;
    int n = idx / K, k = idx - n * K;
    Bt[(size_t)blockIdx.y * total + idx] =
        (h16)W[(size_t)blockIdx.y * total + (size_t)k * N + n];
}

// ====== filter weights: fwt[n][0..19]=filt_W[.][n], [20]=filt_b[n], pad 0 ===
__global__ void filtprep_kernel(const float* __restrict__ filt_W,
                                const float* __restrict__ filt_b,
                                h16* __restrict__ fwt)
{
    int idx = blockIdx.x * 256 + threadIdx.x;
    if (idx >= 384 * 32) return;
    int n = idx >> 5, k = idx & 31;
    float v = 0.f;
    if (k < 20) v = filt_W[k * 384 + n];
    else if (k == 20) v = filt_b[n];
    fwt[idx] = (h16)v;
}

// ====== edge message passing (one block per atom, packed-f16 filter) ======
__global__ __launch_bounds__(128) void edge_kernel(
    const float* __restrict__ dir, const h16* __restrict__ ph,
    const h16* __restrict__ fwt,
    const int* __restrict__ row_start, const int* __restrict__ idx_j,
    const h16* __restrict__ x16, const h16* __restrict__ mu16p,
    const float* __restrict__ mup, float* __restrict__ mun,
    h16* __restrict__ mu16n, float* __restrict__ q)
{
    const int n = blockIdx.x, f = threadIdx.x;
    half2v fa[16], fb[16], fc[16];
    {
        const half8* pa = (const half8*)(fwt + (size_t)f * 32);
        const half8* pb = (const half8*)(fwt + (size_t)(128 + f) * 32);
        const half8* pc = (const half8*)(fwt + (size_t)(256 + f) * 32);
#pragma unroll
        for (int r = 0; r < 3; ++r) {
            *(half8*)&fa[r * 4] = pa[r];
            *(half8*)&fb[r * 4] = pb[r];
            *(half8*)&fc[r * 4] = pc[r];
        }
    }
    float accq = 0.f, am0 = 0.f, am1 = 0.f, am2 = 0.f;
    const int e0 = row_start[n], e1 = row_start[n + 1];
    for (int e = e0; e < e1; ++e) {
        half2v pr[12];
        const h16* pb8 = ph + (size_t)e * 32;
        *(half8*)&pr[0] = *(const half8*)pb8;
        *(half8*)&pr[4] = *(const half8*)(pb8 + 8);
        *(half8*)&pr[8] = *(const half8*)(pb8 + 16);
        half2v A0 = {(h16)0.f, (h16)0.f}, A1 = A0, A2 = A0;
#pragma unroll
        for (int r = 0; r < 11; ++r) {
            A0 = pr[r] * fa[r] + A0;
            A1 = pr[r] * fb[r] + A1;
            A2 = pr[r] * fc[r] + A2;
        }
        float w0 = (float)A0[0] + (float)A0[1];
        float w1 = (float)A1[0] + (float)A1[1];
        float w2 = (float)A2[0] + (float)A2[1];
        int j = idx_j[e];
        float4 g = *(const float4*)&dir[(size_t)e * 4];
        const h16* xb = x16 + (size_t)j * 384;
        const h16* mb = mu16p + (size_t)j * 384;
        float x0 = (float)xb[f], x1 = (float)xb[128 + f], x2 = (float)xb[256 + f];
        accq = fmaf(w0, x0, accq);
        float xw1 = w1 * x1, xw2 = w2 * x2;
        am0 += xw1 * g.x + xw2 * (float)mb[f];
        am1 += xw1 * g.y + xw2 * (float)mb[128 + f];
        am2 += xw1 * g.z + xw2 * (float)mb[256 + f];
    }
    q[(size_t)n * FD + f] += accq;
    size_t b = (size_t)n * 384;
    float m0 = mup[b + f] + am0;
    float m1 = mup[b + 128 + f] + am1;
    float m2 = mup[b + 256 + f] + am2;
    mun[b + f] = m0; mun[b + 128 + f] = m1; mun[b + 256 + f] = m2;
    mu16n[b + f] = (h16)m0; mu16n[b + 128 + f] = (h16)m1; mu16n[b + 256 + f] = (h16)m2;
}

// ====== launch ======
extern "C" void kernel_launch(void* const* d_in, const int* in_sizes, int n_in,
                              void* d_out, int out_size, void* d_ws, size_t ws_size,
                              hipStream_t stream)
{
    const int*   Z       = (const int*)d_in[0];
    const float* R       = (const float*)d_in[1];
    const int*   idx_i   = (const int*)d_in[2];
    const int*   idx_j   = (const int*)d_in[3];
    const float* offsets = (const float*)d_in[4];
    const float* emb     = (const float*)d_in[5];
    const float* filt_W  = (const float*)d_in[6];
    const float* filt_b  = (const float*)d_in[7];
    const float* int_W1  = (const float*)d_in[8];
    const float* int_b1  = (const float*)d_in[9];
    const float* int_W2  = (const float*)d_in[10];
    const float* int_b2  = (const float*)d_in[11];
    const float* mix_Wmu = (const float*)d_in[12];
    const float* mix_W1  = (const float*)d_in[13];
    const float* mix_b1  = (const float*)d_in[14];
    const float* mix_W2  = (const float*)d_in[15];
    const float* mix_b2  = (const float*)d_in[16];

    float* q_out  = (float*)d_out;
    float* mu_out = (float*)d_out + (size_t)NA * FD;

    char* base = (char*)d_ws;
    size_t o = 0;
    auto alloc = [&](size_t bytes) -> void* {
        void* p = base + o;
        o += (bytes + 255) & ~(size_t)255;
        return p;
    };
    float* dir    = (float*)alloc((size_t)NE * 4 * 4);
    h16*   ph     = (h16*)alloc((size_t)NE * 32 * 2);
    h16*   x16    = (h16*)alloc((size_t)NA * 384 * 2);
    h16*   mu16a  = (h16*)alloc((size_t)NA * 384 * 2);
    h16*   mu16b  = (h16*)alloc((size_t)NA * 384 * 2);
    float* mu_ws  = (float*)alloc((size_t)NA * 384 * 4);
    h16*   W1t    = (h16*)alloc((size_t)3 * 128 * 128 * 2);
    h16*   W2t    = (h16*)alloc((size_t)3 * 384 * 128 * 2);
    h16*   WmuT   = (h16*)alloc((size_t)3 * 256 * 128 * 2);
    h16*   mW1t   = (h16*)alloc((size_t)3 * 128 * 256 * 2);
    h16*   mW2t   = (h16*)alloc((size_t)3 * 384 * 128 * 2);
    h16*   fwt    = (h16*)alloc((size_t)384 * 32 * 2);
    int*   row_st = (int*)alloc((size_t)(NA + 1) * 4);

    geom_kernel<<<(NE + 255) / 256, 256, 0, stream>>>(R, idx_i, idx_j, offsets, dir, ph);
    csr_kernel<<<(NA + 256) / 256, 256, 0, stream>>>(idx_i, row_st);
    init_kernel<<<NA, 128, 0, stream>>>(Z, emb, q_out, mu_ws, mu16a);
    wtrans_kernel<<<dim3((128 * 128 + 255) / 256, 3), 256, 0, stream>>>(int_W1, W1t, 128, 128);
    wtrans_kernel<<<dim3((128 * 384 + 255) / 256, 3), 256, 0, stream>>>(int_W2, W2t, 128, 384);
    wtrans_kernel<<<dim3((128 * 256 + 255) / 256, 3), 256, 0, stream>>>(mix_Wmu, WmuT, 128, 256);
    wtrans_kernel<<<dim3((256 * 128 + 255) / 256, 3), 256, 0, stream>>>(mix_W1, mW1t, 256, 128);
    wtrans_kernel<<<dim3((128 * 384 + 255) / 256, 3), 256, 0, stream>>>(mix_W2, mW2t, 128, 384);
    filtprep_kernel<<<(384 * 32 + 255) / 256, 256, 0, stream>>>(filt_W, filt_b, fwt);

    for (int it = 0; it < 3; ++it) {
        const h16*   W1i  = W1t  + (size_t)it * 128 * 128;
        const float* b1i  = int_b1 + (size_t)it * 128;
        const h16*   W2i  = W2t  + (size_t)it * 384 * 128;
        const float* b2i  = int_b2 + (size_t)it * 384;
        const h16*   Wmui = WmuT + (size_t)it * 256 * 128;
        const h16*   mW1i = mW1t + (size_t)it * 128 * 256;
        const float* mb1i = mix_b1 + (size_t)it * 128;
        const h16*   mW2i = mW2t + (size_t)it * 384 * 128;
        const float* mb2i = mix_b2 + (size_t)it * 384;

        float* mu_prev = (it & 1) ? mu_out : mu_ws;
        float* mu_next = (it & 1) ? mu_ws : mu_out;
        h16*   m16p    = (it & 1) ? mu16b : mu16a;
        h16*   m16n    = (it & 1) ? mu16a : mu16b;

        intmlp_kernel<<<NA / 16, 256, 0, stream>>>(q_out, W1i, b1i, W2i, b2i, x16);
        edge_kernel<<<NA, 128, 0, stream>>>(dir, ph, fwt, row_st, idx_j,
                                            x16, m16p, mu_prev, mu_next, m16n, q_out);
        mixfused_kernel<<<NA / 16, 256, 0, stream>>>(m16n, Wmui, mW1i, mb1i, mW2i, mb2i,
                                                     q_out, mu_next, m16n);
    }
}